// Round 10
// baseline (150.022 us; speedup 1.0000x reference)
//
#include <hip/hip_runtime.h>
#include <stdint.h>

typedef unsigned short u16;
typedef __bf16 bf16x8 __attribute__((ext_vector_type(8)));
typedef float f32x4 __attribute__((ext_vector_type(4)));

#define SEQ    1024
#define DMODEL 1024
#define NB     4
#define NH     16
#define DH     64
#define QBLK   128
#define KVB    64
#define LOG2E  1.4426950408889634f

// ---------- bf16 helpers ----------
__device__ __forceinline__ u16 f2bf(float f) {
  uint32_t u = __builtin_bit_cast(uint32_t, f);
  u += 0x7fffu + ((u >> 16) & 1u);   // round-to-nearest-even
  return (u16)(u >> 16);
}
__device__ __forceinline__ u16 f2bf_rz(float f) {   // truncate (p>=0; bias cancels in P/l)
  return (u16)(__builtin_bit_cast(uint32_t, f) >> 16);
}
__device__ __forceinline__ float bf2f(u16 h) {
  uint32_t u = ((uint32_t)h) << 16;
  return __builtin_bit_cast(float, u);
}

#define MFMA16(a, b, c) __builtin_amdgcn_mfma_f32_16x16x32_bf16((a), (b), (c), 0, 0, 0)

// ---------- async global->LDS (16B) ----------
__device__ __forceinline__ void gload_lds16(const u16* g, uintptr_t lds_addr) {
  __builtin_amdgcn_global_load_lds(
      (__attribute__((address_space(1))) void*)(uintptr_t)g,
      (__attribute__((address_space(3))) void*)lds_addr,
      16, 0, 0);
}

// ---------------- rope cos/sin table: tab[t*32+fi] = (cos, sin) ----------------
__global__ void rope_table_kernel(float2* __restrict__ tab) {
  int i = blockIdx.x * blockDim.x + threadIdx.x;   // SEQ*32
  int t = i >> 5, fi = i & 31;
  float inv = exp2f((float)fi * (-13.287712379549449f / 32.0f)); // 10000^(-fi/32)
  float ang = (float)t * inv;
  float sn, cs;
  sincosf(ang, &sn, &cs);
  tab[i] = make_float2(cs, sn);
}

// ---------------- cast f32 -> bf16 (hi only), 8 elems / thread ----------------
__global__ void cast_kernel(const float* __restrict__ src, u16* __restrict__ hi, int n8) {
  int i = blockIdx.x * blockDim.x + threadIdx.x;
  if (i >= n8) return;
  float4 v0 = *(const float4*)(src + (size_t)i * 8);
  float4 v1 = *(const float4*)(src + (size_t)i * 8 + 4);
  union { u16 u[8]; uint4 v; } H;
  H.u[0] = f2bf(v0.x); H.u[1] = f2bf(v0.y); H.u[2] = f2bf(v0.z); H.u[3] = f2bf(v0.w);
  H.u[4] = f2bf(v1.x); H.u[5] = f2bf(v1.y); H.u[6] = f2bf(v1.z); H.u[7] = f2bf(v1.w);
  *(uint4*)(hi + (size_t)i * 8) = H.v;
}

// ---------------- split f32 -> (hi, lo) bf16, 8 elems / thread ----------------
__global__ void split_kernel(const float* __restrict__ src, u16* __restrict__ hi,
                             u16* __restrict__ lo, int n8) {
  int i = blockIdx.x * blockDim.x + threadIdx.x;
  if (i >= n8) return;
  float f[8];
  float4 v0 = *(const float4*)(src + (size_t)i * 8);
  float4 v1 = *(const float4*)(src + (size_t)i * 8 + 4);
  f[0] = v0.x; f[1] = v0.y; f[2] = v0.z; f[3] = v0.w;
  f[4] = v1.x; f[5] = v1.y; f[6] = v1.z; f[7] = v1.w;
  union { u16 u[8]; uint4 v; } H, L;
#pragma unroll
  for (int e = 0; e < 8; ++e) {
    u16 h = f2bf(f[e]);
    H.u[e] = h;
    L.u[e] = f2bf(f[e] - bf2f(h));
  }
  *(uint4*)(hi + (size_t)i * 8) = H.v;
  *(uint4*)(lo + (size_t)i * 8) = L.v;
}

// ---------------- GEMM: C = A @ B^T, BK=64, terms over B only ----------------
// nt=1: C = Ah*Bh. nt=2: C = Ah*Bh + Ah*Bl (A staged once).
// 8-slot XOR swizzle; XCD-aware block swizzle (nwg%8==0).
// mode 0 (+rope): RoPE via shfl_xor pair exchange + table, then hi/lo store.
// mode 1: bf16 transposed out (Vt[col][row]).
struct GemmPtrs {
  const u16* Bh[3]; const u16* Bl[3];
  u16* C0[3]; u16* C1[3];
  int nt[3]; int mode[3]; int rope[3];
};

__global__ __launch_bounds__(256) void gemm_bt_kernel(
    const u16* __restrict__ Ah,
    GemmPtrs P, float* __restrict__ CF, const float2* __restrict__ ropetab,
    int M, int N, int K, int out_f32)
{
  __shared__ __align__(16) u16 sA [128 * 64];   // 16 KB
  __shared__ __align__(16) u16 sBh[128 * 64];   // 16 KB
  __shared__ __align__(16) u16 sBl[128 * 64];   // 16 KB
  const int t = threadIdx.x, lane = t & 63;
  const int wave = t >> 6;
  const int g = lane >> 4, cl = lane & 15;
  const int z = blockIdx.z;
  const u16* Bh = P.Bh[z];
  const u16* Bl = P.Bl[z];
  const int nt = P.nt[z];
  // XCD-aware swizzle: contiguous chunk of wgids per XCD (T1; nwg=256, %8==0)
  const int nwx = gridDim.x;
  int flat = blockIdx.x + nwx * blockIdx.y;
  int cpx = (nwx * gridDim.y) >> 3;
  int swz = (flat & 7) * cpx + (flat >> 3);
  const int n0 = (swz % nwx) * 128, m0 = (swz / nwx) * 128;
  const int wr = wave >> 1, wc = wave & 1;

  // staging: 128x64 u16 tile = 1024 x 16B chunks, 4/thread; linear LDS dest,
  // source col pre-swizzled (rule #21), read-side applies same XOR involution
  int srow[4], scol[4], soff[4];
#pragma unroll
  for (int j = 0; j < 4; ++j) {
    int c = j * 256 + t;
    srow[j] = c >> 3;
    scol[j] = ((c & 7) ^ (srow[j] & 7)) * 8;
    soff[j] = c * 16;
  }

  f32x4 acc[4][4] = {};

  for (int k0 = 0; k0 < K; k0 += 64) {
#pragma unroll
    for (int j = 0; j < 4; ++j) {
      gload_lds16(Ah + (size_t)(m0 + srow[j]) * K + k0 + scol[j], (uintptr_t)sA + soff[j]);
      gload_lds16(Bh + (size_t)(n0 + srow[j]) * K + k0 + scol[j], (uintptr_t)sBh + soff[j]);
    }
    if (nt == 2) {
#pragma unroll
      for (int j = 0; j < 4; ++j)
        gload_lds16(Bl + (size_t)(n0 + srow[j]) * K + k0 + scol[j], (uintptr_t)sBl + soff[j]);
    }
    __syncthreads();   // drains vmcnt(0): staging landed

    bf16x8 af[4][2];
#pragma unroll
    for (int m = 0; m < 4; ++m) {
      int row = wr * 64 + m * 16 + cl;
#pragma unroll
      for (int kk = 0; kk < 2; ++kk)
        af[m][kk] = *(const bf16x8*)&sA[row * 64 + (((kk * 4 + g) ^ (row & 7)) * 8)];
    }
#pragma unroll
    for (int n = 0; n < 4; ++n) {
      int row = wc * 64 + n * 16 + cl;
      int o0 = row * 64 + ((g ^ (row & 7)) * 8);
      int o1 = row * 64 + (((4 + g) ^ (row & 7)) * 8);
      bf16x8 bh0 = *(const bf16x8*)&sBh[o0];
      bf16x8 bh1 = *(const bf16x8*)&sBh[o1];
#pragma unroll
      for (int m = 0; m < 4; ++m) {
        acc[m][n] = MFMA16(af[m][0], bh0, acc[m][n]);
        acc[m][n] = MFMA16(af[m][1], bh1, acc[m][n]);
      }
      if (nt == 2) {
        bf16x8 bl0 = *(const bf16x8*)&sBl[o0];
        bf16x8 bl1 = *(const bf16x8*)&sBl[o1];
#pragma unroll
        for (int m = 0; m < 4; ++m) {
          acc[m][n] = MFMA16(af[m][0], bl0, acc[m][n]);
          acc[m][n] = MFMA16(af[m][1], bl1, acc[m][n]);
        }
      }
    }
    __syncthreads();
  }

  // epilogue: C/D layout col=lane&15, row=(lane>>4)*4+reg  [m89]
  if (out_f32) {
#pragma unroll
    for (int m = 0; m < 4; ++m)
#pragma unroll
      for (int n = 0; n < 4; ++n)
#pragma unroll
        for (int r = 0; r < 4; ++r) {
          int row = m0 + wr * 64 + m * 16 + g * 4 + r;
          int col = n0 + wc * 64 + n * 16 + cl;
          CF[(size_t)row * N + col] = acc[m][n][r];
        }
  } else if (P.mode[z] == 1) {
    u16* VT = P.C0[z];
#pragma unroll
    for (int m = 0; m < 4; ++m)
#pragma unroll
      for (int n = 0; n < 4; ++n) {
        int row0 = m0 + wr * 64 + m * 16 + g * 4;
        int col = n0 + wc * 64 + n * 16 + cl;
        union { u16 u[4]; uint2 v; } pk;
#pragma unroll
        for (int r = 0; r < 4; ++r) pk.u[r] = f2bf(acc[m][n][r]);
        *(uint2*)&VT[(size_t)col * M + row0] = pk.v;
      }
  } else {
    u16* Ch = P.C0[z];
    u16* Cl = P.C1[z];
    const bool dorope = P.rope[z] != 0;   // wave-uniform
    const bool oddl = lane & 1;
#pragma unroll
    for (int m = 0; m < 4; ++m)
#pragma unroll
      for (int n = 0; n < 4; ++n)
#pragma unroll
        for (int r = 0; r < 4; ++r) {
          int row = m0 + wr * 64 + m * 16 + g * 4 + r;
          int col = n0 + wc * 64 + n * 16 + cl;
          float v = acc[m][n][r];
          if (dorope) {
            // pair (2p,2p+1) lives in lanes (cl, cl+1) at same row
            float2 cs = ropetab[(row & (SEQ - 1)) * 32 + ((col >> 1) & 31)];
            float pv = __shfl_xor(v, 1);
            v = oddl ? (pv * cs.y + v * cs.x)    // o' = e*sin + o*cos
                     : (v * cs.x - pv * cs.y);   // e' = e*cos - o*sin
          }
          u16 h = f2bf(v);
          Ch[(size_t)row * N + col] = h;
          Cl[(size_t)row * N + col] = f2bf(v - bf2f(h));
        }
  }
}

// ---------------- flash attention: LDS-shared K/V, 2-phase pipeline, no-max ----------------
// (R8/R9 structure, validated.) Changes: P store via truncation (bias cancels
// in P/l normalization), LDS read offsets hoisted out of the kt loop.
__global__ __launch_bounds__(256, 2) void attn_kernel(
    const u16* __restrict__ Qh, const u16* __restrict__ Ql,
    const u16* __restrict__ Kh, const u16* __restrict__ Kl,
    const u16* __restrict__ Vt,
    u16* __restrict__ Oh)
{
  __shared__ __align__(16) u16 sKh[2][KVB * 64];   // [buf][key][d]  16KB
  __shared__ __align__(16) u16 sKl[2][KVB * 64];   // 16KB
  __shared__ __align__(16) u16 sVt[2][DH * KVB];   // [buf][d][key]  16KB
  __shared__ __align__(16) u16 sP[128 * 72];       // 18KB, wave-private rows

  const int t = threadIdx.x, lane = t & 63, wave = t >> 6;
  const int g = lane >> 4, cl = lane & 15;
  const int h = blockIdx.x & (NH - 1), b = blockIdx.x >> 4;
  const int y = blockIdx.y;
  const int qi = (y < 4) ? (7 - y) : (y - 4);  // paired work balance + heavy-first
  const int q0 = qi * QBLK;
  const size_t rowbase = (size_t)b * SEQ;
  const int colbase = h * DH;
  const int MT = NB * SEQ;

  const u16* Khb = Kh + rowbase * DMODEL + colbase;
  const u16* Klb = Kl + rowbase * DMODEL + colbase;
  const u16* Vtb = Vt + (size_t)(h * DH) * MT + b * SEQ;

  int srow[2], scol[2], soff[2];
#pragma unroll
  for (int j = 0; j < 2; ++j) {
    int c = j * 256 + t;
    srow[j] = c >> 3;
    scol[j] = ((c & 7) ^ (srow[j] & 7)) * 8;
    soff[j] = c * 16;
  }

  // loop-invariant LDS read offsets (kt loop is not unrolled)
  int koff0[4], koff1[4];
#pragma unroll
  for (int n = 0; n < 4; ++n) {
    int row = n * 16 + cl;
    koff0[n] = row * 64 + ((g ^ (row & 7)) * 8);
    koff1[n] = row * 64 + (((4 + g) ^ (row & 7)) * 8);
  }
  int paoff[2][2];
#pragma unroll
  for (int kk = 0; kk < 2; ++kk) {
    paoff[kk][0] = (wave * 32 + cl) * 72 + kk * 32 + g * 8;
    paoff[kk][1] = (wave * 32 + 16 + cl) * 72 + kk * 32 + g * 8;
  }

  // Q fragments (A-op: lane holds A[row=cl][k=g*8+e], second mfma k+32)
  bf16x8 qfh[2][2], qfl[2][2];
#pragma unroll
  for (int mf = 0; mf < 2; ++mf) {
    int qrow = q0 + wave * 32 + mf * 16 + cl;
    const u16* ph = Qh + (rowbase + qrow) * DMODEL + colbase + g * 8;
    const u16* pl = Ql + (rowbase + qrow) * DMODEL + colbase + g * 8;
    qfh[mf][0] = *(const bf16x8*)ph; qfh[mf][1] = *(const bf16x8*)(ph + 32);
    qfl[mf][0] = *(const bf16x8*)pl; qfl[mf][1] = *(const bf16x8*)(pl + 32);
  }

  bf16x8 ones;
#pragma unroll
  for (int e = 0; e < 8; ++e) ones[e] = (__bf16)1.0f;

  f32x4 o_acc[2][4] = {};
  f32x4 o_l[2] = {};

  const int last = 2 * qi + 1;
  const int wrow0 = q0 + wave * 32;
  const int prow0 = wave * 32;

  // prologue: stage tile 0 into buffer 0
#pragma unroll
  for (int j = 0; j < 2; ++j) {
    gload_lds16(Khb + (size_t)srow[j] * DMODEL + scol[j], (uintptr_t)&sKh[0][0] + soff[j]);
    gload_lds16(Klb + (size_t)srow[j] * DMODEL + scol[j], (uintptr_t)&sKl[0][0] + soff[j]);
    gload_lds16(Vtb + (size_t)srow[j] * MT + scol[j],     (uintptr_t)&sVt[0][0] + soff[j]);
  }
  __syncthreads();

  int cur = 0;
  for (int kt = 0; kt <= last; ++kt) {
    const int kv0 = kt * KVB;
    // issue next tile's staging FIRST (hidden under this tile's compute)
    if (kt < last) {
      const int nk = kv0 + KVB;
#pragma unroll
      for (int j = 0; j < 2; ++j) {
        gload_lds16(Khb + (size_t)(nk + srow[j]) * DMODEL + scol[j],
                    (uintptr_t)&sKh[cur ^ 1][0] + soff[j]);
        gload_lds16(Klb + (size_t)(nk + srow[j]) * DMODEL + scol[j],
                    (uintptr_t)&sKl[cur ^ 1][0] + soff[j]);
        gload_lds16(Vtb + (size_t)srow[j] * MT + nk + scol[j],
                    (uintptr_t)&sVt[cur ^ 1][0] + soff[j]);
      }
    }

    const bool skip = (wrow0 + 31) < kv0;   // wave fully masked (diag tiles)
    if (!skip) {
      const bool needmask = (kv0 + 63) > wrow0;

      // QK^T: 3-term split precision from LDS
      f32x4 s[2][4];
      __builtin_amdgcn_s_setprio(1);
#pragma unroll
      for (int n = 0; n < 4; ++n) {
        bf16x8 kh0 = *(const bf16x8*)&sKh[cur][koff0[n]];
        bf16x8 kh1 = *(const bf16x8*)&sKh[cur][koff1[n]];
        bf16x8 kl0 = *(const bf16x8*)&sKl[cur][koff0[n]];
        bf16x8 kl1 = *(const bf16x8*)&sKl[cur][koff1[n]];
#pragma unroll
        for (int mf = 0; mf < 2; ++mf) {
          f32x4 zz = {};
          zz = MFMA16(qfh[mf][0], kh0, zz);
          zz = MFMA16(qfh[mf][1], kh1, zz);
          zz = MFMA16(qfh[mf][0], kl0, zz);
          zz = MFMA16(qfh[mf][1], kl1, zz);
          zz = MFMA16(qfl[mf][0], kh0, zz);
          zz = MFMA16(qfl[mf][1], kh1, zz);
          s[mf][n] = zz;
        }
      }
      __builtin_amdgcn_s_setprio(0);

      // no-max softmax: p = exp2(s*log2e), zeroed past the diagonal
#pragma unroll
      for (int mf = 0; mf < 2; ++mf) {
#pragma unroll
        for (int r = 0; r < 4; ++r) {
          int qg = wrow0 + mf * 16 + g * 4 + r;
          int prow = prow0 + mf * 16 + g * 4 + r;
#pragma unroll
          for (int n = 0; n < 4; ++n) {
            float p = exp2f(s[mf][n][r] * LOG2E);
            if (needmask && (kv0 + n * 16 + cl > qg)) p = 0.0f;
            sP[prow * 72 + n * 16 + cl] = f2bf_rz(p);
          }
        }
      }

      // PV: O += P(32x64)*Vt ; l += P*1 (ones column)
      __builtin_amdgcn_s_setprio(1);
#pragma unroll
      for (int kk = 0; kk < 2; ++kk) {
        bf16x8 pa0 = *(const bf16x8*)&sP[paoff[kk][0]];
        bf16x8 pa1 = *(const bf16x8*)&sP[paoff[kk][1]];
#pragma unroll
        for (int n = 0; n < 4; ++n) {
          bf16x8 vf = *(const bf16x8*)&sVt[cur][(kk == 0) ? koff0[n] : koff1[n]];
          o_acc[0][n] = MFMA16(pa0, vf, o_acc[0][n]);
          o_acc[1][n] = MFMA16(pa1, vf, o_acc[1][n]);
        }
        o_l[0] = MFMA16(pa0, ones, o_l[0]);
        o_l[1] = MFMA16(pa1, ones, o_l[1]);
      }
      __builtin_amdgcn_s_setprio(0);
    }

    __syncthreads();   // drains vmcnt(0): prefetch landed; frees buf cur
    cur ^= 1;
  }

  // epilogue: normalize by l, store bf16 (hi only — Wo is 1-term)
#pragma unroll
  for (int mf = 0; mf < 2; ++mf)
#pragma unroll
    for (int n = 0; n < 4; ++n)
#pragma unroll
      for (int r = 0; r < 4; ++r) {
        float ov = o_acc[mf][n][r] / o_l[mf][r];
        int qrow = q0 + wave * 32 + mf * 16 + g * 4 + r;
        size_t idx = (rowbase + qrow) * DMODEL + colbase + n * 16 + cl;
        Oh[idx] = f2bf(ov);
      }
}

extern "C" void kernel_launch(void* const* d_in, const int* in_sizes, int n_in,
                              void* d_out, int out_size, void* d_ws, size_t ws_size,
                              hipStream_t stream) {
  const float* x  = (const float*)d_in[0];
  const float* Wq = (const float*)d_in[1];
  const float* Wk = (const float*)d_in[2];
  const float* Wv = (const float*)d_in[3];
  const float* Wo = (const float*)d_in[4];
  float* out = (float*)d_out;

  const int M = NB * SEQ;      // 4096
  const int D = DMODEL;        // 1024
  char* ws = (char*)d_ws;
  const size_t MB = 1u << 20;
  u16* xh  = (u16*)(ws + 0 * MB);    // 8 MB
  u16* qh  = (u16*)(ws + 8 * MB);
  u16* ql  = (u16*)(ws + 16 * MB);
  u16* kh  = (u16*)(ws + 24 * MB);
  u16* kl  = (u16*)(ws + 32 * MB);
  u16* vt  = (u16*)(ws + 40 * MB);   // V transposed: [1024 cols][4096 tokens]
  u16* oh  = (u16*)(ws + 48 * MB);
  u16* wqh = (u16*)(ws + 56 * MB);
  u16* wql = (u16*)(ws + 58 * MB);
  u16* wkh = (u16*)(ws + 60 * MB);
  u16* wkl = (u16*)(ws + 62 * MB);
  u16* wvh = (u16*)(ws + 64 * MB);
  u16* woh = (u16*)(ws + 66 * MB);
  float2* ropetab = (float2*)(ws + 68 * MB);   // 256 KB

  // rope table + casts (hi only: x, Wv, Wo) + splits (hi+lo: Wq, Wk)
  rope_table_kernel<<<SEQ * 32 / 256, 256, 0, stream>>>(ropetab);
  cast_kernel<<<(M * D / 8 + 255) / 256, 256, 0, stream>>>(x, xh, M * D / 8);
  split_kernel<<<(D * D / 8 + 255) / 256, 256, 0, stream>>>(Wq, wqh, wql, D * D / 8);
  split_kernel<<<(D * D / 8 + 255) / 256, 256, 0, stream>>>(Wk, wkh, wkl, D * D / 8);
  cast_kernel<<<(D * D / 8 + 255) / 256, 256, 0, stream>>>(Wv, wvh, D * D / 8);
  cast_kernel<<<(D * D / 8 + 255) / 256, 256, 0, stream>>>(Wo, woh, D * D / 8);

  // fused QKV projections: Q,K 2-term + fused RoPE, hi/lo out; V 1-term, Vt out
  {
    GemmPtrs P;
    P.Bh[0] = wqh; P.Bh[1] = wkh; P.Bh[2] = wvh;
    P.Bl[0] = wql; P.Bl[1] = wkl; P.Bl[2] = nullptr;
    P.C0[0] = qh;  P.C0[1] = kh;  P.C0[2] = vt;
    P.C1[0] = ql;  P.C1[1] = kl;  P.C1[2] = nullptr;
    P.nt[0] = 2;   P.nt[1] = 2;   P.nt[2] = 1;
    P.mode[0] = 0; P.mode[1] = 0; P.mode[2] = 1;
    P.rope[0] = 1; P.rope[1] = 1; P.rope[2] = 0;
    gemm_bt_kernel<<<dim3(D / 128, M / 128, 3), 256, 0, stream>>>(
        xh, P, nullptr, ropetab, M, D, D, 0);
  }

  // causal flash attention: 512 blocks of 4 waves, pair-balanced heavy-first
  attn_kernel<<<dim3(NH * NB, 8), 256, 0, stream>>>(qh, ql, kh, kl, vt, oh);

  // output projection, 1-term bf16, f32 out
  {
    GemmPtrs P;
    P.Bh[0] = woh; P.Bh[1] = woh; P.Bh[2] = woh;
    P.Bl[0] = nullptr; P.Bl[1] = nullptr; P.Bl[2] = nullptr;
    P.C0[0] = nullptr; P.C0[1] = nullptr; P.C0[2] = nullptr;
    P.C1[0] = nullptr; P.C1[1] = nullptr; P.C1[2] = nullptr;
    P.nt[0] = 1;   P.nt[1] = 1;   P.nt[2] = 1;
    P.mode[0] = 0; P.mode[1] = 0; P.mode[2] = 0;
    P.rope[0] = 0; P.rope[1] = 0; P.rope[2] = 0;
    gemm_bt_kernel<<<dim3(D / 128, M / 128, 1), 256, 0, stream>>>(
        oh, P, out, ropetab, M, D, D, 1);
  }
}